// Round 1
// baseline (605.960 us; speedup 1.0000x reference)
//
#include <hip/hip_runtime.h>
#include <hip/hip_bf16.h>

typedef float f32x4 __attribute__((ext_vector_type(4)));
typedef __bf16 bfv8 __attribute__((ext_vector_type(8)));
typedef short s16x8 __attribute__((ext_vector_type(8)));

constexpr int Bc = 4, Sc = 2048, Ec = 1024, Hc = 16, Dc = 64;
constexpr int Mc = Bc * Sc;  // 8192 rows

__device__ __forceinline__ ushort f2bf(float f) {
  __hip_bfloat16 h = __float2bfloat16(f);
  return __builtin_bit_cast(ushort, h);
}

// ---------------- weight convert + transpose: W[K][N] f32 -> WT[N][K] bf16 ----
__global__ __launch_bounds__(256) void wcvt_kernel(const float* __restrict__ W,
                                                   ushort* __restrict__ WT,
                                                   int K, int N) {
  __shared__ float t[32][33];
  int k0 = blockIdx.x * 32, n0 = blockIdx.y * 32;
  int tx = threadIdx.x, ty = threadIdx.y;  // (32,8)
#pragma unroll
  for (int i = 0; i < 32; i += 8)
    t[ty + i][tx] = W[(size_t)(k0 + ty + i) * N + n0 + tx];
  __syncthreads();
#pragma unroll
  for (int i = 0; i < 32; i += 8)
    WT[(size_t)(n0 + ty + i) * K + k0 + tx] = f2bf(t[tx][ty + i]);
}

// ---------------- LayerNorm: row of 1024, one block per row ------------------
__global__ __launch_bounds__(256) void ln_kernel(const float* in,
                                                 const float* __restrict__ g,
                                                 const float* __restrict__ bb,
                                                 float* of, ushort* ob) {
  int row = blockIdx.x;
  int t = threadIdx.x;
  float4 x = reinterpret_cast<const float4*>(in + (size_t)row * Ec)[t];
  float s = x.x + x.y + x.z + x.w;
  float q = x.x * x.x + x.y * x.y + x.z * x.z + x.w * x.w;
#pragma unroll
  for (int o = 32; o > 0; o >>= 1) {
    s += __shfl_down(s, o);
    q += __shfl_down(q, o);
  }
  __shared__ float red[10];
  int wv = t >> 6;
  if ((t & 63) == 0) { red[wv] = s; red[4 + wv] = q; }
  __syncthreads();
  if (t == 0) {
    float S = red[0] + red[1] + red[2] + red[3];
    float Q = red[4] + red[5] + red[6] + red[7];
    float mu = S * (1.f / Ec);
    float var = Q * (1.f / Ec) - mu * mu;
    red[8] = mu;
    red[9] = rsqrtf(var + 1e-5f);
  }
  __syncthreads();
  float mu = red[8], rs = red[9];
  float4 gg = reinterpret_cast<const float4*>(g)[t];
  float4 b4 = reinterpret_cast<const float4*>(bb)[t];
  float4 y;
  y.x = (x.x - mu) * rs * gg.x + b4.x;
  y.y = (x.y - mu) * rs * gg.y + b4.y;
  y.z = (x.z - mu) * rs * gg.z + b4.z;
  y.w = (x.w - mu) * rs * gg.w + b4.w;
  reinterpret_cast<float4*>(of + (size_t)row * Ec)[t] = y;
  ushort4 u;
  u.x = f2bf(y.x); u.y = f2bf(y.y); u.z = f2bf(y.z); u.w = f2bf(y.w);
  reinterpret_cast<ushort4*>(ob + (size_t)row * Ec)[t] = u;
}

// ---------------- GEMM: C[M,N] = A[M,K](bf16) * BT[N,K]^T(bf16) + epilogue ---
// MODE 0: qkv -> bf16 [B,H,S,D] layout, (acc+bias)*qscale
// MODE 1: f32 out = acc + bias + resid (row-major)
// MODE 2: bf16 out = gelu(acc + bias) (row-major)
template <int MODE>
__global__ __launch_bounds__(256) void gemm_kernel(int M, int N, int K,
                                                   const ushort* __restrict__ A,
                                                   const ushort* __restrict__ BT,
                                                   const float* __restrict__ bias,
                                                   const float* resid, float* outF,
                                                   ushort* outB, float qscale) {
  constexpr int LDT = 40;  // 32 + 8 pad (80B row stride: 16B-aligned, conflict-light)
  __shared__ __align__(16) ushort As[128 * LDT];
  __shared__ __align__(16) ushort Bs[128 * LDT];
  const int tid = threadIdx.x;
  const int lane = tid & 63, wave = tid >> 6;
  const int wr = wave >> 1, wc = wave & 1;
  const int m0 = blockIdx.y * 128, n0 = blockIdx.x * 128;
  const int fr = lane & 15, fq = lane >> 4;

  f32x4 acc[4][4];
#pragma unroll
  for (int i = 0; i < 4; i++)
#pragma unroll
    for (int j = 0; j < 4; j++) acc[i][j] = f32x4{0.f, 0.f, 0.f, 0.f};

  const int sr = tid >> 2, sc2 = (tid & 3) * 8;
  const ushort* Ag = A + (size_t)(m0 + sr) * K + sc2;
  const ushort* Bg = BT + (size_t)(n0 + sr) * K + sc2;

  for (int k0 = 0; k0 < K; k0 += 32) {
    *reinterpret_cast<int4*>(&As[sr * LDT + sc2]) =
        *reinterpret_cast<const int4*>(Ag + k0);
    *reinterpret_cast<int4*>(&As[(sr + 64) * LDT + sc2]) =
        *reinterpret_cast<const int4*>(Ag + (size_t)64 * K + k0);
    *reinterpret_cast<int4*>(&Bs[sr * LDT + sc2]) =
        *reinterpret_cast<const int4*>(Bg + k0);
    *reinterpret_cast<int4*>(&Bs[(sr + 64) * LDT + sc2]) =
        *reinterpret_cast<const int4*>(Bg + (size_t)64 * K + k0);
    __syncthreads();
    bfv8 af[4], bf[4];
#pragma unroll
    for (int m = 0; m < 4; m++)
      af[m] = *reinterpret_cast<const bfv8*>(&As[(wr * 64 + m * 16 + fr) * LDT + fq * 8]);
#pragma unroll
    for (int n = 0; n < 4; n++)
      bf[n] = *reinterpret_cast<const bfv8*>(&Bs[(wc * 64 + n * 16 + fr) * LDT + fq * 8]);
#pragma unroll
    for (int m = 0; m < 4; m++)
#pragma unroll
      for (int n = 0; n < 4; n++)
        acc[m][n] = __builtin_amdgcn_mfma_f32_16x16x32_bf16(af[m], bf[n], acc[m][n], 0, 0, 0);
    __syncthreads();
  }

#pragma unroll
  for (int m = 0; m < 4; m++) {
#pragma unroll
    for (int n = 0; n < 4; n++) {
#pragma unroll
      for (int r = 0; r < 4; r++) {
        int row = m0 + wr * 64 + m * 16 + fq * 4 + r;
        int col = n0 + wc * 64 + n * 16 + fr;
        float vacc = acc[m][n][r] + bias[col];
        if constexpr (MODE == 0) {
          vacc *= qscale;
          int b = row >> 11, sIdx = row & (Sc - 1);
          int h = col >> 6, d = col & (Dc - 1);
          outB[(((size_t)b * Hc + h) * Sc + sIdx) * Dc + d] = f2bf(vacc);
        } else if constexpr (MODE == 1) {
          size_t idx = (size_t)row * N + col;
          outF[idx] = vacc + resid[idx];
        } else {
          vacc = 0.5f * vacc * (1.f + erff(vacc * 0.70710678118f));
          outB[(size_t)row * N + col] = f2bf(vacc);
        }
      }
    }
  }
}

// ---------------- Flash attention: q,k,v [B,H,S,D] bf16 -> o [B,S,E] bf16 ----
// q pre-scaled by 1/sqrt(D). Swapped QK^T (S^T = K*Q^T) so softmax row-reduce
// is in-lane + 2 shfls. P goes through LDS to become the PV A-operand.
__global__ __launch_bounds__(256) void attn_kernel(const ushort* __restrict__ q,
                                                   const ushort* __restrict__ k,
                                                   const ushort* __restrict__ v,
                                                   ushort* __restrict__ o) {
  const int blk = blockIdx.x;
  const int qb = blk & 31;  // S/64 q-blocks
  const int bh = blk >> 5;  // b*H + h
  const int tid = threadIdx.x, lane = tid & 63, wave = tid >> 6;
  const int fr = lane & 15, fq = lane >> 4;
  const size_t base = (size_t)bh * Sc * Dc;
  const int q0 = qb * 64 + wave * 16;

  __shared__ __align__(16) ushort Ks[32 * 72];   // [key][d] pad->72
  __shared__ __align__(16) ushort Vt[64 * 40];   // [d][key] pad->40
  __shared__ __align__(16) ushort Ps[4][16 * 40];

  const ushort* qp = q + base + (size_t)(q0 + fr) * Dc + fq * 8;
  bfv8 qf0 = *reinterpret_cast<const bfv8*>(qp);
  bfv8 qf1 = *reinterpret_cast<const bfv8*>(qp + 32);

  f32x4 oacc[4];
#pragma unroll
  for (int i = 0; i < 4; i++) oacc[i] = f32x4{0.f, 0.f, 0.f, 0.f};
  float mrow = -1e30f, lrow = 0.f;

  const int srK = tid >> 3;       // 0..31
  const int scK = (tid & 7) * 8;  // 0..56

  for (int kt = 0; kt < Sc / 32; ++kt) {
    const int key0 = kt * 32;
    *reinterpret_cast<int4*>(&Ks[srK * 72 + scK]) =
        *reinterpret_cast<const int4*>(k + base + (size_t)(key0 + srK) * Dc + scK);
    {
      s16x8 vv = *reinterpret_cast<const s16x8*>(v + base + (size_t)(key0 + srK) * Dc + scK);
#pragma unroll
      for (int j = 0; j < 8; j++) Vt[(scK + j) * 40 + srK] = (ushort)vv[j];
    }
    __syncthreads();

    f32x4 sf[2];
    sf[0] = f32x4{0.f, 0.f, 0.f, 0.f};
    sf[1] = f32x4{0.f, 0.f, 0.f, 0.f};
#pragma unroll
    for (int t = 0; t < 2; t++) {
      bfv8 kf0 = *reinterpret_cast<const bfv8*>(&Ks[(t * 16 + fr) * 72 + fq * 8]);
      bfv8 kf1 = *reinterpret_cast<const bfv8*>(&Ks[(t * 16 + fr) * 72 + 32 + fq * 8]);
      sf[t] = __builtin_amdgcn_mfma_f32_16x16x32_bf16(kf0, qf0, sf[t], 0, 0, 0);
      sf[t] = __builtin_amdgcn_mfma_f32_16x16x32_bf16(kf1, qf1, sf[t], 0, 0, 0);
    }
    // lane holds S^T[key0 + t*16 + fq*4 + r][qrow = fr]
    float mt = sf[0][0];
#pragma unroll
    for (int t = 0; t < 2; t++)
#pragma unroll
      for (int r = 0; r < 4; r++) mt = fmaxf(mt, sf[t][r]);
    mt = fmaxf(mt, __shfl_xor(mt, 16));
    mt = fmaxf(mt, __shfl_xor(mt, 32));
    float mnew = fmaxf(mrow, mt);
    float alpha = __expf(mrow - mnew);
    float p[2][4];
    float rsum = 0.f;
#pragma unroll
    for (int t = 0; t < 2; t++)
#pragma unroll
      for (int r = 0; r < 4; r++) {
        p[t][r] = __expf(sf[t][r] - mnew);
        rsum += p[t][r];
      }
    rsum += __shfl_xor(rsum, 16);
    rsum += __shfl_xor(rsum, 32);
    lrow = lrow * alpha + rsum;
    mrow = mnew;
#pragma unroll
    for (int t = 0; t < 2; t++)
#pragma unroll
      for (int r = 0; r < 4; r++)
        Ps[wave][fr * 40 + t * 16 + fq * 4 + r] = f2bf(p[t][r]);
    float ar[4];
#pragma unroll
    for (int r = 0; r < 4; r++) ar[r] = __shfl(alpha, fq * 4 + r);
#pragma unroll
    for (int dt = 0; dt < 4; dt++)
#pragma unroll
      for (int r = 0; r < 4; r++) oacc[dt][r] *= ar[r];
    bfv8 pf = *reinterpret_cast<const bfv8*>(&Ps[wave][fr * 40 + fq * 8]);
#pragma unroll
    for (int dt = 0; dt < 4; dt++) {
      bfv8 vf = *reinterpret_cast<const bfv8*>(&Vt[(dt * 16 + fr) * 40 + fq * 8]);
      oacc[dt] = __builtin_amdgcn_mfma_f32_16x16x32_bf16(pf, vf, oacc[dt], 0, 0, 0);
    }
    __syncthreads();
  }

  const int b = bh >> 4, h = bh & 15;
  float linv[4];
#pragma unroll
  for (int r = 0; r < 4; r++) linv[r] = 1.f / __shfl(lrow, fq * 4 + r);
#pragma unroll
  for (int dt = 0; dt < 4; dt++)
#pragma unroll
    for (int r = 0; r < 4; r++) {
      int sIdx = q0 + fq * 4 + r;
      o[((size_t)(b * Sc + sIdx)) * Ec + h * 64 + dt * 16 + fr] =
          f2bf(oacc[dt][r] * linv[r]);
    }
}

// -----------------------------------------------------------------------------
extern "C" void kernel_launch(void* const* d_in, const int* in_sizes, int n_in,
                              void* d_out, int out_size, void* d_ws, size_t ws_size,
                              hipStream_t stream) {
  const float* inp = (const float*)d_in[0];
  const float* ln1g = (const float*)d_in[1];
  const float* ln1b = (const float*)d_in[2];
  const float* Wq = (const float*)d_in[3];
  const float* bq = (const float*)d_in[4];
  const float* Wk = (const float*)d_in[5];
  const float* bk = (const float*)d_in[6];
  const float* Wv = (const float*)d_in[7];
  const float* bv = (const float*)d_in[8];
  const float* Wo = (const float*)d_in[9];
  const float* bo = (const float*)d_in[10];
  const float* ln2g = (const float*)d_in[11];
  const float* ln2b = (const float*)d_in[12];
  const float* W1 = (const float*)d_in[13];
  const float* b1 = (const float*)d_in[14];
  const float* W2 = (const float*)d_in[15];
  const float* b2 = (const float*)d_in[16];

  char* wsb = (char*)d_ws;
  size_t off = 0;
  auto alloc = [&](size_t bytes) {
    char* p = wsb + off;
    off += (bytes + 255) & ~(size_t)255;
    return p;
  };
  float* xf = (float*)alloc((size_t)Mc * Ec * 4);       // LN1 out -> y -> x2 (f32)
  ushort* xb = (ushort*)alloc((size_t)Mc * Ec * 2);     // LN1 bf16 -> LN2 bf16
  ushort* qbuf = (ushort*)alloc((size_t)Mc * Ec * 2);
  ushort* kbuf = (ushort*)alloc((size_t)Mc * Ec * 2);
  ushort* vbuf = (ushort*)alloc((size_t)Mc * Ec * 2);
  ushort* abuf = (ushort*)alloc((size_t)Mc * Ec * 2);
  ushort* h1 = (ushort*)alloc((size_t)Mc * 2 * Ec * 2);
  ushort* WqT = (ushort*)alloc((size_t)Ec * Ec * 2);
  ushort* WkT = (ushort*)alloc((size_t)Ec * Ec * 2);
  ushort* WvT = (ushort*)alloc((size_t)Ec * Ec * 2);
  ushort* WoT = (ushort*)alloc((size_t)Ec * Ec * 2);
  ushort* W1T = (ushort*)alloc((size_t)Ec * 2 * Ec * 2);
  ushort* W2T = (ushort*)alloc((size_t)Ec * 2 * Ec * 2);
  (void)in_sizes; (void)n_in; (void)out_size; (void)ws_size;

  dim3 tb(32, 8);
  wcvt_kernel<<<dim3(Ec / 32, Ec / 32), tb, 0, stream>>>(Wq, WqT, Ec, Ec);
  wcvt_kernel<<<dim3(Ec / 32, Ec / 32), tb, 0, stream>>>(Wk, WkT, Ec, Ec);
  wcvt_kernel<<<dim3(Ec / 32, Ec / 32), tb, 0, stream>>>(Wv, WvT, Ec, Ec);
  wcvt_kernel<<<dim3(Ec / 32, Ec / 32), tb, 0, stream>>>(Wo, WoT, Ec, Ec);
  wcvt_kernel<<<dim3(Ec / 32, 2 * Ec / 32), tb, 0, stream>>>(W1, W1T, Ec, 2 * Ec);
  wcvt_kernel<<<dim3(2 * Ec / 32, Ec / 32), tb, 0, stream>>>(W2, W2T, 2 * Ec, Ec);

  ln_kernel<<<Mc, 256, 0, stream>>>(inp, ln1g, ln1b, xf, xb);

  gemm_kernel<0><<<dim3(Ec / 128, Mc / 128), 256, 0, stream>>>(
      Mc, Ec, Ec, xb, WqT, bq, nullptr, nullptr, qbuf, 0.125f);
  gemm_kernel<0><<<dim3(Ec / 128, Mc / 128), 256, 0, stream>>>(
      Mc, Ec, Ec, xb, WkT, bk, nullptr, nullptr, kbuf, 1.f);
  gemm_kernel<0><<<dim3(Ec / 128, Mc / 128), 256, 0, stream>>>(
      Mc, Ec, Ec, xb, WvT, bv, nullptr, nullptr, vbuf, 1.f);

  attn_kernel<<<Bc * Hc * (Sc / 64), 256, 0, stream>>>(qbuf, kbuf, vbuf, abuf);

  gemm_kernel<1><<<dim3(Ec / 128, Mc / 128), 256, 0, stream>>>(
      Mc, Ec, Ec, abuf, WoT, bo, xf, xf, nullptr, 1.f);

  ln_kernel<<<Mc, 256, 0, stream>>>(xf, ln2g, ln2b, xf, xb);

  gemm_kernel<2><<<dim3(2 * Ec / 128, Mc / 128), 256, 0, stream>>>(
      Mc, 2 * Ec, Ec, xb, W1T, b1, nullptr, nullptr, h1, 1.f);

  gemm_kernel<1><<<dim3(Ec / 128, Mc / 128), 256, 0, stream>>>(
      Mc, Ec, 2 * Ec, h1, W2T, b2, xf, (float*)d_out, nullptr, 1.f);
}

// Round 2
// 473.747 us; speedup vs baseline: 1.2791x; 1.2791x over previous
//
#include <hip/hip_runtime.h>
#include <hip/hip_bf16.h>

typedef float f32x4 __attribute__((ext_vector_type(4)));
typedef __bf16 bfv8 __attribute__((ext_vector_type(8)));

constexpr int Bc = 4, Sc = 2048, Ec = 1024, Hc = 16, Dc = 64;
constexpr int Mc = Bc * Sc;  // 8192 rows

__device__ __forceinline__ ushort f2bf(float f) {
  __hip_bfloat16 h = __float2bfloat16(f);
  return __builtin_bit_cast(ushort, h);
}

typedef __attribute__((address_space(1))) unsigned int as1_u32;
typedef __attribute__((address_space(3))) unsigned int as3_u32;
__device__ __forceinline__ void cp16(const ushort* g, ushort* l) {
  // async global->LDS, 16B per lane; LDS dest = wave-uniform base + lane*16
  __builtin_amdgcn_global_load_lds((as1_u32*)g, (as3_u32*)l, 16, 0, 0);
}

// ---------------- weight convert + transpose: W[K][N] f32 -> WT[N][K] bf16 ----
__global__ __launch_bounds__(256) void wcvt_kernel(const float* __restrict__ W,
                                                   ushort* __restrict__ WT,
                                                   int K, int N) {
  __shared__ float t[32][33];
  int k0 = blockIdx.x * 32, n0 = blockIdx.y * 32;
  int tx = threadIdx.x, ty = threadIdx.y;  // (32,8)
#pragma unroll
  for (int i = 0; i < 32; i += 8)
    t[ty + i][tx] = W[(size_t)(k0 + ty + i) * N + n0 + tx];
  __syncthreads();
#pragma unroll
  for (int i = 0; i < 32; i += 8)
    WT[(size_t)(n0 + ty + i) * K + k0 + tx] = f2bf(t[tx][ty + i]);
}

// ---------------- LayerNorm: row of 1024, one block per row ------------------
__global__ __launch_bounds__(256) void ln_kernel(const float* in,
                                                 const float* __restrict__ g,
                                                 const float* __restrict__ bb,
                                                 float* of, ushort* ob) {
  int row = blockIdx.x;
  int t = threadIdx.x;
  float4 x = reinterpret_cast<const float4*>(in + (size_t)row * Ec)[t];
  float s = x.x + x.y + x.z + x.w;
  float q = x.x * x.x + x.y * x.y + x.z * x.z + x.w * x.w;
#pragma unroll
  for (int o = 32; o > 0; o >>= 1) {
    s += __shfl_down(s, o);
    q += __shfl_down(q, o);
  }
  __shared__ float red[10];
  int wv = t >> 6;
  if ((t & 63) == 0) { red[wv] = s; red[4 + wv] = q; }
  __syncthreads();
  if (t == 0) {
    float S = red[0] + red[1] + red[2] + red[3];
    float Q = red[4] + red[5] + red[6] + red[7];
    float mu = S * (1.f / Ec);
    float var = Q * (1.f / Ec) - mu * mu;
    red[8] = mu;
    red[9] = rsqrtf(var + 1e-5f);
  }
  __syncthreads();
  float mu = red[8], rs = red[9];
  float4 gg = reinterpret_cast<const float4*>(g)[t];
  float4 b4 = reinterpret_cast<const float4*>(bb)[t];
  float4 y;
  y.x = (x.x - mu) * rs * gg.x + b4.x;
  y.y = (x.y - mu) * rs * gg.y + b4.y;
  y.z = (x.z - mu) * rs * gg.z + b4.z;
  y.w = (x.w - mu) * rs * gg.w + b4.w;
  reinterpret_cast<float4*>(of + (size_t)row * Ec)[t] = y;
  ushort4 u;
  u.x = f2bf(y.x); u.y = f2bf(y.y); u.z = f2bf(y.z); u.w = f2bf(y.w);
  reinterpret_cast<ushort4*>(ob + (size_t)row * Ec)[t] = u;
}

// ---------------- GEMM: C[M,N] = A[M,K](bf16) * BT[N,K]^T(bf16) + epilogue ---
// MODE 0: (acc+bias)*qscale -> bf16 [B,H,S,D] (Q,K)
// MODE 1: f32 out = acc + bias + resid (row-major)
// MODE 2: bf16 out = gelu(acc + bias) (row-major)
// MODE 3: (acc+bias) -> bf16 V^T [B,H,D,S] packed ushort4
template <int MODE>
__global__ __launch_bounds__(256) void gemm_kernel(int M, int N, int K,
                                                   const ushort* __restrict__ A,
                                                   const ushort* __restrict__ BT,
                                                   const float* __restrict__ bias,
                                                   const float* resid, float* outF,
                                                   ushort* outB, float qscale) {
  constexpr int BK = 32;
  __shared__ __align__(16) ushort As[128 * BK];
  __shared__ __align__(16) ushort Bs[128 * BK];
  const int tid = threadIdx.x;
  const int lane = tid & 63, wave = tid >> 6;
  const int wr = wave >> 1, wc = wave & 1;
  const int fr = lane & 15, fq = lane >> 4;
  // XCD-chunked swizzle: contiguous M-range per XCD (A slice + B panel fit L2)
  const int nx = gridDim.x;
  int flat = blockIdx.x + nx * blockIdx.y;
  int cpx = (nx * gridDim.y) >> 3;  // all launches have nwg % 8 == 0
  int work = (flat & 7) * cpx + (flat >> 3);
  const int n0 = (work % nx) * 128, m0 = (work / nx) * 128;

  f32x4 acc[4][4];
#pragma unroll
  for (int i = 0; i < 4; i++)
#pragma unroll
    for (int j = 0; j < 4; j++) acc[i][j] = f32x4{0.f, 0.f, 0.f, 0.f};

  const int srow = lane >> 2, schk = lane & 3;
  const ushort* Ag = A + (size_t)(m0 + wave * 32 + srow) * K + schk * 8;
  const ushort* Bg = BT + (size_t)(n0 + wave * 32 + srow) * K + schk * 8;

  for (int k0 = 0; k0 < K; k0 += BK) {
#pragma unroll
    for (int i = 0; i < 2; ++i) {
      cp16(Ag + (size_t)(i * 16) * K + k0, &As[(wave * 32 + i * 16) * BK]);
      cp16(Bg + (size_t)(i * 16) * K + k0, &Bs[(wave * 32 + i * 16) * BK]);
    }
    __syncthreads();
    bfv8 af[4], bf[4];
#pragma unroll
    for (int m = 0; m < 4; m++)
      af[m] = *reinterpret_cast<const bfv8*>(&As[(wr * 64 + m * 16 + fr) * BK + fq * 8]);
#pragma unroll
    for (int n = 0; n < 4; n++)
      bf[n] = *reinterpret_cast<const bfv8*>(&Bs[(wc * 64 + n * 16 + fr) * BK + fq * 8]);
#pragma unroll
    for (int m = 0; m < 4; m++)
#pragma unroll
      for (int n = 0; n < 4; n++)
        acc[m][n] = __builtin_amdgcn_mfma_f32_16x16x32_bf16(af[m], bf[n], acc[m][n], 0, 0, 0);
    __syncthreads();
  }

#pragma unroll
  for (int m = 0; m < 4; m++) {
#pragma unroll
    for (int n = 0; n < 4; n++) {
      const int row0 = m0 + wr * 64 + m * 16 + fq * 4;
      const int col = n0 + wc * 64 + n * 16 + fr;
      const float bb = bias[col];
      if constexpr (MODE == 3) {
        int b = row0 >> 11, sIdx = row0 & (Sc - 1);
        int h = col >> 6, d = col & (Dc - 1);
        ushort4 u;
        u.x = f2bf(acc[m][n][0] + bb);
        u.y = f2bf(acc[m][n][1] + bb);
        u.z = f2bf(acc[m][n][2] + bb);
        u.w = f2bf(acc[m][n][3] + bb);
        *reinterpret_cast<ushort4*>(
            &outB[(((size_t)b * Hc + h) * Dc + d) * Sc + sIdx]) = u;
      } else {
#pragma unroll
        for (int r = 0; r < 4; r++) {
          int row = row0 + r;
          float vacc = acc[m][n][r] + bb;
          if constexpr (MODE == 0) {
            vacc *= qscale;
            int b = row >> 11, sIdx = row & (Sc - 1);
            int h = col >> 6, d = col & (Dc - 1);
            outB[(((size_t)b * Hc + h) * Sc + sIdx) * Dc + d] = f2bf(vacc);
          } else if constexpr (MODE == 1) {
            size_t idx = (size_t)row * N + col;
            outF[idx] = vacc + resid[idx];
          } else {
            vacc = 0.5f * vacc * (1.f + erff(vacc * 0.70710678118f));
            outB[(size_t)row * N + col] = f2bf(vacc);
          }
        }
      }
    }
  }
}

// ---------------- Flash attention ------------------------------------------
// q,k: [B,H,S,D] bf16 (q pre-scaled by 1/sqrt(D)); vt: [B,H,D,S] bf16.
// Swapped QK^T (S^T = K*Q^T) so softmax row-reduce is in-lane + 2 shfls.
// KV tile = 64 keys; V already transposed globally -> coalesced conflict-free
// staging; P round-trips LDS packed as ushort4.
__global__ __launch_bounds__(256) void attn_kernel(const ushort* __restrict__ q,
                                                   const ushort* __restrict__ k,
                                                   const ushort* __restrict__ vt,
                                                   ushort* __restrict__ o) {
  int flat = blockIdx.x;                     // 2048 blocks
  int swz = (flat & 7) * 256 + (flat >> 3);  // XCD-chunked: 8 heads per XCD
  const int qb = swz & 31;
  const int bh = swz >> 5;
  const int tid = threadIdx.x, lane = tid & 63, wave = tid >> 6;
  const int fr = lane & 15, fq = lane >> 4;
  const size_t base = (size_t)bh * Sc * Dc;
  const int q0 = qb * 64 + wave * 16;

  __shared__ __align__(16) ushort Ks[64 * 72];      // [key][d] pad->72
  __shared__ __align__(16) ushort Vt[64 * 72];      // [d][key] pad->72
  __shared__ __align__(16) ushort Ps[4][16 * 72];   // per-wave [q][key]

  const ushort* qp = q + base + (size_t)(q0 + fr) * Dc + fq * 8;
  bfv8 qf0 = *reinterpret_cast<const bfv8*>(qp);
  bfv8 qf1 = *reinterpret_cast<const bfv8*>(qp + 32);

  f32x4 oacc[4];
#pragma unroll
  for (int i = 0; i < 4; i++) oacc[i] = f32x4{0.f, 0.f, 0.f, 0.f};
  float mrow = -1e30f, lrow = 0.f;

  const int r8 = tid >> 3;   // 0..31 (row per 8 threads)
  const int c8 = tid & 7;    // 16B chunk within 128B row

  for (int kt = 0; kt < Sc / 64; ++kt) {
    const int key0 = kt * 64;
#pragma unroll
    for (int it = 0; it < 2; ++it) {
      int row = it * 32 + r8;
      *reinterpret_cast<int4*>(&Ks[row * 72 + c8 * 8]) =
          *reinterpret_cast<const int4*>(k + base + (size_t)(key0 + row) * Dc + c8 * 8);
      *reinterpret_cast<int4*>(&Vt[row * 72 + c8 * 8]) =
          *reinterpret_cast<const int4*>(vt + base + (size_t)row * Sc + key0 + c8 * 8);
    }
    __syncthreads();

    f32x4 sf[4];
#pragma unroll
    for (int t = 0; t < 4; ++t) {
      sf[t] = f32x4{0.f, 0.f, 0.f, 0.f};
      bfv8 kf0 = *reinterpret_cast<const bfv8*>(&Ks[(t * 16 + fr) * 72 + fq * 8]);
      bfv8 kf1 = *reinterpret_cast<const bfv8*>(&Ks[(t * 16 + fr) * 72 + 32 + fq * 8]);
      sf[t] = __builtin_amdgcn_mfma_f32_16x16x32_bf16(kf0, qf0, sf[t], 0, 0, 0);
      sf[t] = __builtin_amdgcn_mfma_f32_16x16x32_bf16(kf1, qf1, sf[t], 0, 0, 0);
    }
    // lane holds S[q=fr][key = key0 + t*16 + fq*4 + r]
    float mt = sf[0][0];
#pragma unroll
    for (int t = 0; t < 4; ++t)
#pragma unroll
      for (int r = 0; r < 4; ++r) mt = fmaxf(mt, sf[t][r]);
    mt = fmaxf(mt, __shfl_xor(mt, 16));
    mt = fmaxf(mt, __shfl_xor(mt, 32));
    float mnew = fmaxf(mrow, mt);
    float alpha = __expf(mrow - mnew);
    float p[4][4];
    float rsum = 0.f;
#pragma unroll
    for (int t = 0; t < 4; ++t)
#pragma unroll
      for (int r = 0; r < 4; ++r) {
        p[t][r] = __expf(sf[t][r] - mnew);
        rsum += p[t][r];
      }
    rsum += __shfl_xor(rsum, 16);
    rsum += __shfl_xor(rsum, 32);
    lrow = lrow * alpha + rsum;
    mrow = mnew;
#pragma unroll
    for (int t = 0; t < 4; ++t) {
      ushort4 pu;
      pu.x = f2bf(p[t][0]);
      pu.y = f2bf(p[t][1]);
      pu.z = f2bf(p[t][2]);
      pu.w = f2bf(p[t][3]);
      *reinterpret_cast<ushort4*>(&Ps[wave][fr * 72 + t * 16 + fq * 4]) = pu;
    }
    float ar[4];
#pragma unroll
    for (int r = 0; r < 4; ++r) ar[r] = __shfl(alpha, fq * 4 + r);
#pragma unroll
    for (int dt = 0; dt < 4; ++dt)
#pragma unroll
      for (int r = 0; r < 4; ++r) oacc[dt][r] *= ar[r];
    bfv8 pf0 = *reinterpret_cast<const bfv8*>(&Ps[wave][fr * 72 + fq * 8]);
    bfv8 pf1 = *reinterpret_cast<const bfv8*>(&Ps[wave][fr * 72 + 32 + fq * 8]);
#pragma unroll
    for (int dt = 0; dt < 4; ++dt) {
      bfv8 vf0 = *reinterpret_cast<const bfv8*>(&Vt[(dt * 16 + fr) * 72 + fq * 8]);
      bfv8 vf1 = *reinterpret_cast<const bfv8*>(&Vt[(dt * 16 + fr) * 72 + 32 + fq * 8]);
      oacc[dt] = __builtin_amdgcn_mfma_f32_16x16x32_bf16(pf0, vf0, oacc[dt], 0, 0, 0);
      oacc[dt] = __builtin_amdgcn_mfma_f32_16x16x32_bf16(pf1, vf1, oacc[dt], 0, 0, 0);
    }
    __syncthreads();
  }

  const int b = bh >> 4, h = bh & 15;
  float linv[4];
#pragma unroll
  for (int r = 0; r < 4; ++r) linv[r] = 1.f / __shfl(lrow, fq * 4 + r);
#pragma unroll
  for (int dt = 0; dt < 4; ++dt)
#pragma unroll
    for (int r = 0; r < 4; ++r) {
      int sIdx = q0 + fq * 4 + r;
      o[((size_t)(b * Sc + sIdx)) * Ec + h * 64 + dt * 16 + fr] =
          f2bf(oacc[dt][r] * linv[r]);
    }
}

// -----------------------------------------------------------------------------
extern "C" void kernel_launch(void* const* d_in, const int* in_sizes, int n_in,
                              void* d_out, int out_size, void* d_ws, size_t ws_size,
                              hipStream_t stream) {
  const float* inp = (const float*)d_in[0];
  const float* ln1g = (const float*)d_in[1];
  const float* ln1b = (const float*)d_in[2];
  const float* Wq = (const float*)d_in[3];
  const float* bq = (const float*)d_in[4];
  const float* Wk = (const float*)d_in[5];
  const float* bk = (const float*)d_in[6];
  const float* Wv = (const float*)d_in[7];
  const float* bv = (const float*)d_in[8];
  const float* Wo = (const float*)d_in[9];
  const float* bo = (const float*)d_in[10];
  const float* ln2g = (const float*)d_in[11];
  const float* ln2b = (const float*)d_in[12];
  const float* W1 = (const float*)d_in[13];
  const float* b1 = (const float*)d_in[14];
  const float* W2 = (const float*)d_in[15];
  const float* b2 = (const float*)d_in[16];

  char* wsb = (char*)d_ws;
  size_t off = 0;
  auto alloc = [&](size_t bytes) {
    char* p = wsb + off;
    off += (bytes + 255) & ~(size_t)255;
    return p;
  };
  float* xf = (float*)alloc((size_t)Mc * Ec * 4);
  ushort* xb = (ushort*)alloc((size_t)Mc * Ec * 2);
  ushort* qbuf = (ushort*)alloc((size_t)Mc * Ec * 2);
  ushort* kbuf = (ushort*)alloc((size_t)Mc * Ec * 2);
  ushort* vtbuf = (ushort*)alloc((size_t)Mc * Ec * 2);
  ushort* abuf = (ushort*)alloc((size_t)Mc * Ec * 2);
  ushort* h1 = (ushort*)alloc((size_t)Mc * 2 * Ec * 2);
  ushort* WqT = (ushort*)alloc((size_t)Ec * Ec * 2);
  ushort* WkT = (ushort*)alloc((size_t)Ec * Ec * 2);
  ushort* WvT = (ushort*)alloc((size_t)Ec * Ec * 2);
  ushort* WoT = (ushort*)alloc((size_t)Ec * Ec * 2);
  ushort* W1T = (ushort*)alloc((size_t)Ec * 2 * Ec * 2);
  ushort* W2T = (ushort*)alloc((size_t)Ec * 2 * Ec * 2);
  (void)in_sizes; (void)n_in; (void)out_size; (void)ws_size;

  dim3 tb(32, 8);
  wcvt_kernel<<<dim3(Ec / 32, Ec / 32), tb, 0, stream>>>(Wq, WqT, Ec, Ec);
  wcvt_kernel<<<dim3(Ec / 32, Ec / 32), tb, 0, stream>>>(Wk, WkT, Ec, Ec);
  wcvt_kernel<<<dim3(Ec / 32, Ec / 32), tb, 0, stream>>>(Wv, WvT, Ec, Ec);
  wcvt_kernel<<<dim3(Ec / 32, Ec / 32), tb, 0, stream>>>(Wo, WoT, Ec, Ec);
  wcvt_kernel<<<dim3(Ec / 32, 2 * Ec / 32), tb, 0, stream>>>(W1, W1T, Ec, 2 * Ec);
  wcvt_kernel<<<dim3(2 * Ec / 32, Ec / 32), tb, 0, stream>>>(W2, W2T, 2 * Ec, Ec);

  ln_kernel<<<Mc, 256, 0, stream>>>(inp, ln1g, ln1b, xf, xb);

  gemm_kernel<0><<<dim3(Ec / 128, Mc / 128), 256, 0, stream>>>(
      Mc, Ec, Ec, xb, WqT, bq, nullptr, nullptr, qbuf, 0.125f);
  gemm_kernel<0><<<dim3(Ec / 128, Mc / 128), 256, 0, stream>>>(
      Mc, Ec, Ec, xb, WkT, bk, nullptr, nullptr, kbuf, 1.f);
  gemm_kernel<3><<<dim3(Ec / 128, Mc / 128), 256, 0, stream>>>(
      Mc, Ec, Ec, xb, WvT, bv, nullptr, nullptr, vtbuf, 1.f);

  attn_kernel<<<Bc * Hc * (Sc / 64), 256, 0, stream>>>(qbuf, kbuf, vtbuf, abuf);

  gemm_kernel<1><<<dim3(Ec / 128, Mc / 128), 256, 0, stream>>>(
      Mc, Ec, Ec, abuf, WoT, bo, xf, xf, nullptr, 1.f);

  ln_kernel<<<Mc, 256, 0, stream>>>(xf, ln2g, ln2b, xf, xb);

  gemm_kernel<2><<<dim3(2 * Ec / 128, Mc / 128), 256, 0, stream>>>(
      Mc, 2 * Ec, Ec, xb, W1T, b1, nullptr, nullptr, h1, 1.f);

  gemm_kernel<1><<<dim3(Ec / 128, Mc / 128), 256, 0, stream>>>(
      Mc, Ec, 2 * Ec, h1, W2T, b2, xf, (float*)d_out, nullptr, 1.f);
}